// Round 3
// baseline (844.537 us; speedup 1.0000x reference)
//
#include <hip/hip_runtime.h>

#define NUM_NODES 50000
#define WINDOW 8
#define DIM 256
#define BATCH 8192
#define BANK4 ((long)NUM_NODES * WINDOW * (DIM / 4))   // 25.6M float4
#define TS4   ((long)NUM_NODES * WINDOW / 4)           // 100K float4

// -------- K1: per-node occurrence count (order-independent atomics) ------------------
__global__ void count_kernel(const int* __restrict__ idx, int* __restrict__ count) {
    int bi = blockIdx.x * blockDim.x + threadIdx.x;
    if (bi < BATCH) atomicAdd(&count[idx[bi]], 1);
}

// -------- K2: classify — unique nodes resolved directly, duplicates listed -----------
__global__ void classify_kernel(const int* __restrict__ idx, const int* __restrict__ ptr,
                                const int* __restrict__ count,
                                int* __restrict__ slotcode,
                                int* __restrict__ duplist, int* __restrict__ dupN) {
    int bi = blockIdx.x * blockDim.x + threadIdx.x;
    if (bi >= BATCH) return;
    int node = idx[bi];
    int c    = count[node];
    if (c == 1) {
        slotcode[bi] = node * WINDOW + (ptr[node] & (WINDOW - 1));
    } else {
        duplist[atomicAdd(dupN, 1)] = bi;
    }
}

// -------- K3: rank duplicates (single block; ndup ~ 150-300 here) --------------------
__global__ void dup_rank_kernel(const int* __restrict__ idx, const int* __restrict__ ptr,
                                const int* __restrict__ count,
                                const int* __restrict__ duplist, const int* __restrict__ dupN,
                                int* __restrict__ slotcode) {
    __shared__ int spos[BATCH];            // 32 KiB; only first n entries used
    int n = *dupN;
    for (int k = threadIdx.x; k < n; k += blockDim.x) spos[k] = duplist[k];
    __syncthreads();
    for (int k = threadIdx.x; k < n; k += blockDim.x) {
        int p    = spos[k];
        int node = idx[p];
        int rank = 0;
        for (int m = 0; m < n; ++m) {
            int q = spos[m];
            rank += (q < p && idx[q] == node);
        }
        int c = count[node];
        slotcode[p] = (rank >= c - WINDOW)
                      ? node * WINDOW + ((ptr[node] + rank) & (WINDOW - 1))
                      : -1;
    }
}

// -------- K4: pure streaming copy (the HBM floor) + folded ptr_new -------------------
__global__ void __launch_bounds__(256)
copy_kernel(const float4* __restrict__ bank4, const float4* __restrict__ ts4,
            const int* __restrict__ ptr, const int* __restrict__ count,
            float4* __restrict__ out_bank4, float4* __restrict__ out_ts4,
            float* __restrict__ out_ptr) {
    const long tid = (long)blockIdx.x * blockDim.x + threadIdx.x;
    const long nth = (long)gridDim.x * blockDim.x;
    for (long i = tid; i < BANK4; i += nth) out_bank4[i] = bank4[i];
    for (long i = tid; i < TS4;   i += nth) out_ts4[i]   = ts4[i];
    if (tid < NUM_NODES) out_ptr[tid] = (float)(ptr[tid] + count[tid]);
}

// -------- K5: scatter the 8192 winning rows over the copy ----------------------------
__global__ void scatter_kernel(const int* __restrict__ slotcode,
                               const float4* __restrict__ nrep4,
                               const float* __restrict__ t,
                               float4* __restrict__ out_bank4,
                               float* __restrict__ out_ts) {
    int bi   = blockIdx.x;
    int code = slotcode[bi];
    if (code < 0) return;
    int lane = threadIdx.x;            // 64 lanes x float4 = 256 floats = one row
    out_bank4[(size_t)code * (DIM / 4) + lane] = nrep4[(size_t)bi * (DIM / 4) + lane];
    if (lane == 0) out_ts[code] = t[bi];
}

extern "C" void kernel_launch(void* const* d_in, const int* in_sizes, int n_in,
                              void* d_out, int out_size, void* d_ws, size_t ws_size,
                              hipStream_t stream) {
    const float* bank       = (const float*)d_in[0];
    const float* timestamps = (const float*)d_in[1];
    const float* nrep       = (const float*)d_in[2];
    const float* t          = (const float*)d_in[3];
    const int*   ptr        = (const int*)  d_in[4];
    const int*   idx        = (const int*)  d_in[5];

    float* out_bank = (float*)d_out;
    float* out_ts   = out_bank + (size_t)NUM_NODES * WINDOW * DIM;
    float* out_ptr  = out_ts   + (size_t)NUM_NODES * WINDOW;

    // ws layout: count[50000] | dupN[1] | duplist[8192] | slotcode[8192]
    int* count    = (int*)d_ws;
    int* dupN     = count + NUM_NODES;
    int* duplist  = dupN + 1;
    int* slotcode = duplist + BATCH;

    // re-init accumulators every call (ws is not re-poisoned between replays)
    hipMemsetAsync(count, 0, (NUM_NODES + 1) * sizeof(int), stream);

    count_kernel   <<<(BATCH + 255) / 256, 256, 0, stream>>>(idx, count);
    classify_kernel<<<(BATCH + 255) / 256, 256, 0, stream>>>(idx, ptr, count,
                                                             slotcode, duplist, dupN);
    dup_rank_kernel<<<1, 256, 0, stream>>>(idx, ptr, count, duplist, dupN, slotcode);

    copy_kernel<<<2048, 256, 0, stream>>>(
        (const float4*)bank, (const float4*)timestamps, ptr, count,
        (float4*)out_bank, (float4*)out_ts, out_ptr);

    scatter_kernel<<<BATCH, 64, 0, stream>>>(slotcode, (const float4*)nrep, t,
                                             (float4*)out_bank, out_ts);
}

// Round 4
// 303.857 us; speedup vs baseline: 2.7794x; 2.7794x over previous
//
#include <hip/hip_runtime.h>

#define NUM_NODES 50000
#define WINDOW 8
#define DIM 256
#define BATCH 8192
#define BANK4 ((long)NUM_NODES * WINDOW * (DIM / 4))   // 25.6M float4
#define TS4   ((long)NUM_NODES * WINDOW / 4)           // 100K float4

// -------- K1: per-node occurrence count (order-independent atomics) ------------------
__global__ void count_kernel(const int* __restrict__ idx, int* __restrict__ count) {
    int bi = blockIdx.x * blockDim.x + threadIdx.x;
    if (bi < BATCH) atomicAdd(&count[idx[bi]], 1);
}

// -------- K2: classify — unique nodes resolved directly, duplicates listed -----------
// count==1 => rank=0, slot = ptr[node] % 8, always a winner.
// count>1  => append batch position to duplist (append order irrelevant; K3 ranks by
//             batch position, so the result is deterministic).
__global__ void classify_kernel(const int* __restrict__ idx, const int* __restrict__ ptr,
                                const int* __restrict__ count,
                                int* __restrict__ slotcode,
                                int* __restrict__ duplist, int* __restrict__ dupN) {
    int bi = blockIdx.x * blockDim.x + threadIdx.x;
    if (bi >= BATCH) return;
    int node = idx[bi];
    int c    = count[node];
    if (c == 1) {
        slotcode[bi] = node * WINDOW + (ptr[node] & (WINDOW - 1));
    } else {
        duplist[atomicAdd(dupN, 1)] = bi;
    }
}

// -------- K3: rank duplicates — ALL operands in LDS, 32 blocks ------------------------
// n ~= 1240 for this distribution (max 8192). Each block stages the full dup list
// (positions + node ids) into LDS, then each thread ranks one element with an O(n)
// LDS-only scan. rank = #{q in duplist : idx[q]==node && q<p} == full batch rank,
// since ALL occurrences of a duplicated node are in the list.
__global__ void __launch_bounds__(256)
dup_rank_kernel(const int* __restrict__ idx, const int* __restrict__ ptr,
                const int* __restrict__ count,
                const int* __restrict__ duplist, const int* __restrict__ dupN,
                int* __restrict__ slotcode) {
    __shared__ int spos [BATCH];           // 32 KiB
    __shared__ int snode[BATCH];           // 32 KiB
    int n = *dupN;
    for (int k = threadIdx.x; k < n; k += blockDim.x) {
        int p = duplist[k];
        spos [k] = p;
        snode[k] = idx[p];
    }
    __syncthreads();

    int k = blockIdx.x * blockDim.x + threadIdx.x;
    if (k >= n) return;
    int p    = spos[k];
    int node = snode[k];
    int rank = 0;
    for (int m = 0; m < n; ++m)
        rank += (spos[m] < p && snode[m] == node);

    int c = count[node];
    slotcode[p] = (rank >= c - WINDOW)                    // winner: last writer per slot
                  ? node * WINDOW + ((ptr[node] + rank) & (WINDOW - 1))
                  : -1;
}

// -------- K4: pure streaming copy (the HBM floor) + folded ptr_new -------------------
__global__ void __launch_bounds__(256)
copy_kernel(const float4* __restrict__ bank4, const float4* __restrict__ ts4,
            const int* __restrict__ ptr, const int* __restrict__ count,
            float4* __restrict__ out_bank4, float4* __restrict__ out_ts4,
            float* __restrict__ out_ptr) {
    const long tid = (long)blockIdx.x * blockDim.x + threadIdx.x;
    const long nth = (long)gridDim.x * blockDim.x;
    for (long i = tid; i < BANK4; i += nth) out_bank4[i] = bank4[i];
    for (long i = tid; i < TS4;   i += nth) out_ts4[i]   = ts4[i];
    if (tid < NUM_NODES) out_ptr[tid] = (float)(ptr[tid] + count[tid]);
}

// -------- K5: scatter the 8192 winning rows over the copy ----------------------------
__global__ void scatter_kernel(const int* __restrict__ slotcode,
                               const float4* __restrict__ nrep4,
                               const float* __restrict__ t,
                               float4* __restrict__ out_bank4,
                               float* __restrict__ out_ts) {
    int bi   = blockIdx.x;
    int code = slotcode[bi];
    if (code < 0) return;
    int lane = threadIdx.x;            // 64 lanes x float4 = 256 floats = one row
    out_bank4[(size_t)code * (DIM / 4) + lane] = nrep4[(size_t)bi * (DIM / 4) + lane];
    if (lane == 0) out_ts[code] = t[bi];
}

extern "C" void kernel_launch(void* const* d_in, const int* in_sizes, int n_in,
                              void* d_out, int out_size, void* d_ws, size_t ws_size,
                              hipStream_t stream) {
    const float* bank       = (const float*)d_in[0];
    const float* timestamps = (const float*)d_in[1];
    const float* nrep       = (const float*)d_in[2];
    const float* t          = (const float*)d_in[3];
    const int*   ptr        = (const int*)  d_in[4];
    const int*   idx        = (const int*)  d_in[5];

    float* out_bank = (float*)d_out;
    float* out_ts   = out_bank + (size_t)NUM_NODES * WINDOW * DIM;
    float* out_ptr  = out_ts   + (size_t)NUM_NODES * WINDOW;

    // ws layout: count[50000] | dupN[1] | duplist[8192] | slotcode[8192]
    int* count    = (int*)d_ws;
    int* dupN     = count + NUM_NODES;
    int* duplist  = dupN + 1;
    int* slotcode = duplist + BATCH;

    // re-init accumulators every call (ws is not re-poisoned between replays)
    hipMemsetAsync(count, 0, (NUM_NODES + 1) * sizeof(int), stream);

    count_kernel   <<<(BATCH + 255) / 256, 256, 0, stream>>>(idx, count);
    classify_kernel<<<(BATCH + 255) / 256, 256, 0, stream>>>(idx, ptr, count,
                                                             slotcode, duplist, dupN);
    dup_rank_kernel<<<(BATCH + 255) / 256, 256, 0, stream>>>(idx, ptr, count,
                                                             duplist, dupN, slotcode);

    copy_kernel<<<2048, 256, 0, stream>>>(
        (const float4*)bank, (const float4*)timestamps, ptr, count,
        (float4*)out_bank, (float4*)out_ts, out_ptr);

    scatter_kernel<<<BATCH, 64, 0, stream>>>(slotcode, (const float4*)nrep, t,
                                             (float4*)out_bank, out_ts);
}